// Round 2
// baseline (119.246 us; speedup 1.0000x reference)
//
#include <hip/hip_runtime.h>
#include <hip/hip_bf16.h>

// Problem constants (GraphRestrictedBoltzmannMachine)
#define V_SZ   131072
#define H_SZ   8192
#define DEG_SZ 64
#define B_SZ   128
#define N_TOT  139264   // V + H

// ---------------------------------------------------------------------------
// Pass 1: pack sign bits of s (fp32 +-1, shape [B=128, N]) transposed:
// pk[c] = uint4 (128 bits), bit b of word w (b = 32w + r) = 1 iff s[b][c] < 0.
// Grid: 512 blocks x 256 threads; thread t packs column c = blk*256 + t,
// reading 128 coalesced fp32 (lane-consecutive columns -> 256B/wave/row).
// ---------------------------------------------------------------------------
__global__ __launch_bounds__(256) void pack_signs(
    const float* __restrict__ s, uint4* __restrict__ pk)
{
    const int c = blockIdx.x * 256 + threadIdx.x;
    const float* __restrict__ col = s + c;
    unsigned w[4];
#pragma unroll
    for (int wq = 0; wq < 4; ++wq) {
        unsigned acc = 0u;
#pragma unroll
        for (int r = 0; r < 32; ++r) {
            float v = col[(size_t)(wq * 32 + r) * N_TOT];
            acc |= (__float_as_uint(v) >> 31) << r;
        }
        w[wq] = acc;
    }
    pk[c] = make_uint4(w[0], w[1], w[2], w[3]);
}

// ---------------------------------------------------------------------------
// Pass 2: out[b][j] = linear[V+j] + sum_{k<64} (+-1) * q[64j+k]
// Grid: 512 blocks x 512 threads; block handles 16 hidden units x 128 batches.
// Thread t: kh = t>>8 (k-half), r = t&255, jl = r>>4 (local j), o = r&15
// (batch octet: b = o*8 + bb), word w = o>>2, sub-byte sb = (o&3)*8.
// LDS bits planes [w][jl*68 + k]: plane stride 1104, row stride 68 -> the
// 16 distinct ds_read_b128 addresses per wave land 2-way/bank = free (m136).
// ---------------------------------------------------------------------------
__global__ __launch_bounds__(512, 4) void field_kernel(
    const unsigned int* __restrict__ pk,            // packed signs, V*4 words
    const int* __restrict__ adj,                    // E
    const float* __restrict__ q,                    // E
    const float* __restrict__ linear,               // N
    float* __restrict__ out)                        // B x H
{
    __shared__ unsigned int bits_lds[4 * 1104];     // 17664 B
    __shared__ float        q_lds[16 * 68];         //  4352 B
    __shared__ float        red_lds[256 * 9];       //  9216 B (stride 9: no conflicts)
    __shared__ float        out_lds[128 * 17];      //  8704 B (stride 17: no conflicts)

    const int t      = threadIdx.x;
    const int j0     = blockIdx.x * 16;
    const int e_base = j0 * 64;

    // ---- Stage A: stage 1024 edges (adj gather of packed words + q) ----
    {
        const int e   = t * 2;              // even => pairs never cross j rows
        const int jl  = e >> 6;
        const int k   = e & 63;
        const int idx = jl * 68 + k;        // even => 8B-aligned LDS writes

        int2 a2 = *(const int2*)(adj + e_base + e);
        uint4 b0 = *(const uint4*)(pk + a2.x * 4);
        uint4 b1 = *(const uint4*)(pk + a2.y * 4);

        *(uint2*)&bits_lds[0 * 1104 + idx] = make_uint2(b0.x, b1.x);
        *(uint2*)&bits_lds[1 * 1104 + idx] = make_uint2(b0.y, b1.y);
        *(uint2*)&bits_lds[2 * 1104 + idx] = make_uint2(b0.z, b1.z);
        *(uint2*)&bits_lds[3 * 1104 + idx] = make_uint2(b0.w, b1.w);

        float2 qv = *(const float2*)(q + e_base + e);
        *(float2*)&q_lds[idx] = qv;
    }
    __syncthreads();

    // ---- Compute ----
    const int kh = t >> 8;
    const int r  = t & 255;
    const int jl = r >> 4;
    const int o  = r & 15;
    const int w  = o >> 2;
    const int sb = (o & 3) * 8;

    float acc[8];
#pragma unroll
    for (int i = 0; i < 8; ++i) acc[i] = 0.0f;

    const unsigned int* __restrict__ plane = &bits_lds[w * 1104 + jl * 68];
    const float* __restrict__ qrow = &q_lds[jl * 68];
    const int k0 = kh * 32;

#pragma unroll
    for (int ks = 0; ks < 32; ks += 4) {
        const int k = k0 + ks;
        uint4  u4 = *(const uint4*)(plane + k);
        float4 q4 = *(const float4*)(qrow + k);
        {
            unsigned us = u4.x >> sb;
            unsigned qb = __float_as_uint(q4.x);
#pragma unroll
            for (int bb = 0; bb < 8; ++bb)
                acc[bb] += __uint_as_float(qb ^ ((us << (31 - bb)) & 0x80000000u));
        }
        {
            unsigned us = u4.y >> sb;
            unsigned qb = __float_as_uint(q4.y);
#pragma unroll
            for (int bb = 0; bb < 8; ++bb)
                acc[bb] += __uint_as_float(qb ^ ((us << (31 - bb)) & 0x80000000u));
        }
        {
            unsigned us = u4.z >> sb;
            unsigned qb = __float_as_uint(q4.z);
#pragma unroll
            for (int bb = 0; bb < 8; ++bb)
                acc[bb] += __uint_as_float(qb ^ ((us << (31 - bb)) & 0x80000000u));
        }
        {
            unsigned us = u4.w >> sb;
            unsigned qb = __float_as_uint(q4.w);
#pragma unroll
            for (int bb = 0; bb < 8; ++bb)
                acc[bb] += __uint_as_float(qb ^ ((us << (31 - bb)) & 0x80000000u));
        }
    }

    // ---- Reduce the two k-halves, add linear, store via LDS transpose ----
    if (kh == 1) {
#pragma unroll
        for (int i = 0; i < 8; ++i) red_lds[r * 9 + i] = acc[i];
    }
    __syncthreads();
    if (kh == 0) {
        const float lin = linear[V_SZ + j0 + jl];
#pragma unroll
        for (int bb = 0; bb < 8; ++bb) {
            float v = acc[bb] + red_lds[r * 9 + bb] + lin;
            out_lds[(o * 8 + bb) * 17 + jl] = v;
        }
    }
    __syncthreads();
    {
        const int row  = t >> 2;    // batch b (0..127)
        const int quad = t & 3;     // 4-col group of the 16-col tile
        const float* src = &out_lds[row * 17 + quad * 4];
        float4 v = make_float4(src[0], src[1], src[2], src[3]);
        *(float4*)(out + row * H_SZ + j0 + quad * 4) = v;
    }
}

extern "C" void kernel_launch(void* const* d_in, const int* in_sizes, int n_in,
                              void* d_out, int out_size, void* d_ws, size_t ws_size,
                              hipStream_t stream) {
    const float* s         = (const float*)d_in[0];
    const float* linear    = (const float*)d_in[1];
    const float* quadratic = (const float*)d_in[2];
    const int*   flat_adj  = (const int*)d_in[3];
    float*       out       = (float*)d_out;

    // Workspace: packed sign bits, V * 16 B = 2 MiB.
    uint4* pk = (uint4*)d_ws;

    hipLaunchKernelGGL(pack_signs, dim3(512), dim3(256), 0, stream, s, pk);
    hipLaunchKernelGGL(field_kernel, dim3(512), dim3(512), 0, stream,
                       (const unsigned int*)d_ws, flat_adj, quadratic, linear, out);
}